// Round 11
// baseline (897.348 us; speedup 1.0000x reference)
//
#include <hip/hip_runtime.h>
#include <hip/hip_bf16.h>
#include <math.h>

#define NB 4
#define NS 2048
#define ND 512
#define NH 8
#define NDK 64
#define NDV 64

typedef __attribute__((ext_vector_type(8))) short short8;
typedef __attribute__((ext_vector_type(4))) float f32x4;
typedef __attribute__((ext_vector_type(4))) unsigned int u32x4;

__device__ __forceinline__ unsigned short f2bfu(float f) {
  // round-to-nearest-even bf16 (inputs finite)
  unsigned int u = __builtin_bit_cast(unsigned int, f);
  unsigned int rounding = 0x7fffu + ((u >> 16) & 1u);
  return (unsigned short)((u + rounding) >> 16);
}
__device__ __forceinline__ float bfu2f(unsigned short u) {
  return __builtin_bit_cast(float, (unsigned int)u << 16);
}

// ---------------- prep kernels ----------------

// x [M][512] f32 -> xcat [M][1536] bf16 = [xhi | xhi | xlo]
__global__ void k_make_xcat(const float* __restrict__ in, unsigned short* __restrict__ out,
                            int n4) {
  int i = blockIdx.x * 256 + threadIdx.x;
  if (i >= n4) return;
  int row = i >> 7, col = (i & 127) * 4;  // 512/4 = 128 chunks per row
  float4 f = reinterpret_cast<const float4*>(in)[i];
  ushort4 h, l;
  h.x = f2bfu(f.x); h.y = f2bfu(f.y); h.z = f2bfu(f.z); h.w = f2bfu(f.w);
  l.x = f2bfu(f.x - bfu2f(h.x)); l.y = f2bfu(f.y - bfu2f(h.y));
  l.z = f2bfu(f.z - bfu2f(h.z)); l.w = f2bfu(f.w - bfu2f(h.w));
  ushort4* o = reinterpret_cast<ushort4*>(out + (size_t)row * 1536);
  o[col / 4] = h;
  o[(col + 512) / 4] = h;
  o[(col + 1024) / 4] = l;
}

// W [R][C] f32 -> Wcat [C][3R] bf16 rows = [Whi^T | Wlo^T | Whi^T]
__global__ void k_transpose_split(const float* __restrict__ src, unsigned short* __restrict__ dst,
                                  int R, int C) {
  __shared__ float t[32][33];
  int bx = blockIdx.x * 32, by = blockIdx.y * 32;
  int tx = threadIdx.x, ty = threadIdx.y;
  for (int i = 0; i < 32; i += 8)
    t[ty + i][tx] = src[(size_t)(by + ty + i) * C + bx + tx];
  __syncthreads();
  for (int i = 0; i < 32; i += 8) {
    float f = t[tx][ty + i];
    unsigned short h = f2bfu(f);
    unsigned short l = f2bfu(f - bfu2f(h));
    size_t base = (size_t)(bx + ty + i) * (3 * R) + by + tx;
    dst[base] = h;
    dst[base + R] = l;
    dst[base + 2 * R] = h;
  }
}

// ---------------- NT MFMA GEMM: C = A * Bt^T + bias ----------------
template <int MODE>
__global__ __launch_bounds__(256) void k_gemm_nt(
    const unsigned short* __restrict__ A, const unsigned short* __restrict__ Bt,
    const float* __restrict__ bias, void* __restrict__ outp, unsigned short* __restrict__ outlo,
    int M, int N, int K) {
  __shared__ __align__(16) unsigned short As[64][88];
  __shared__ __align__(16) unsigned short Bs[64][88];
  const int tid = threadIdx.x;
  const int m0 = blockIdx.y * 64;
  const int n0 = blockIdx.x * 64;
  const int wave = tid >> 6, lane = tid & 63;
  const int lm = lane & 15, lg = lane >> 4;

  f32x4 acc[4];
  for (int n = 0; n < 4; n++) acc[n] = (f32x4){0.f, 0.f, 0.f, 0.f};

  for (int k0 = 0; k0 < K; k0 += 64) {
    for (int it = 0; it < 2; it++) {
      int c = tid + it * 256;
      int row = c >> 3, col = (c & 7) * 8;
      *reinterpret_cast<short8*>(&As[row][col]) =
          *reinterpret_cast<const short8*>(A + (size_t)(m0 + row) * K + k0 + col);
      *reinterpret_cast<short8*>(&Bs[row][col]) =
          *reinterpret_cast<const short8*>(Bt + (size_t)(n0 + row) * K + k0 + col);
    }
    __syncthreads();
#pragma unroll
    for (int ks = 0; ks < 2; ks++) {
      short8 a = *reinterpret_cast<const short8*>(&As[wave * 16 + lm][ks * 32 + lg * 8]);
#pragma unroll
      for (int n = 0; n < 4; n++) {
        short8 b = *reinterpret_cast<const short8*>(&Bs[n * 16 + lm][ks * 32 + lg * 8]);
        acc[n] = __builtin_amdgcn_mfma_f32_16x16x32_bf16(a, b, acc[n], 0, 0, 0);
      }
    }
    __syncthreads();
  }

#pragma unroll
  for (int n = 0; n < 4; n++) {
    int gn = n0 + n * 16 + lm;
    float bv = bias[gn];
#pragma unroll
    for (int r = 0; r < 4; r++) {
      int gm = m0 + wave * 16 + lg * 4 + r;
      float v = acc[n][r] + bv;
      if (MODE == 3) {
        reinterpret_cast<float*>(outp)[(size_t)gm * ND + gn] = v;
      } else {
        int b = gm >> 11, s = gm & (NS - 1);
        int h = gn >> 6, d = gn & 63;
        unsigned short hb = f2bfu(v);
        unsigned short lb = f2bfu(v - bfu2f(hb));
        size_t idx;
        if (MODE == 0)
          idx = (((size_t)b * NH + h) * NS + s) * NDK + d;
        else
          idx = (((size_t)b * NH + h) * NDV + d) * NS + s;
        reinterpret_cast<unsigned short*>(outp)[idx] = hb;
        outlo[idx] = lb;
      }
    }
  }
}

// ---------------- fused sparse attention: register-resident scores (v2) ----------------
// 1024 threads (16 waves), 2 blocks/CU. One block = one (b,h) + 16 q rows.
// Wave w owns kv slice [w*128, w*128+128). Swapped QK^T (mfma(K,Q)): every lane's
// 32 scores belong to q = lane&15, kv = w*128 + kt*16 + (lane>>4)*4 + r.
// st[8] (32 VGPR) is the only cross-phase register state -> no scratch spill.
__global__ __launch_bounds__(1024, 8) void k_sparse_attn(
    const unsigned short* __restrict__ Qh, const unsigned short* __restrict__ Ql,
    const unsigned short* __restrict__ Kh, const unsigned short* __restrict__ Kl,
    const unsigned short* __restrict__ Vth, const unsigned short* __restrict__ Vtl,
    unsigned short* __restrict__ attn) {
  __shared__ float part[5][16][16];                 // [round][wave][q] reduction partials
  __shared__ __align__(16) float red[16][16][68];   // [wave][q][dv] PV partials (+4 pad)

  const int tid = threadIdx.x;
  const int wave = tid >> 6, lane = tid & 63;
  const int lm = lane & 15, lg = lane >> 4;

  // bijective XCD swizzle: 4096 wgs -> XCD x gets logical ids [x*512, x*512+512)
  const int orig = blockIdx.x;
  const int blk = (orig & 7) * 512 + (orig >> 3);
  const int qt = blk & (NS / 16 - 1);
  const int bh = blk >> 7;  // NS/16 == 128
  const int q0 = qt * 16;

  const size_t qoff = ((size_t)bh * NS + q0) * NDK;
  const unsigned short* Kph = Kh + (size_t)bh * NS * NDK;
  const unsigned short* Kpl = Kl + (size_t)bh * NS * NDK;
  const unsigned short* Vph = Vth + (size_t)bh * NDV * NS;
  const unsigned short* Vpl = Vtl + (size_t)bh * NDV * NS;
  const int kvbase = wave * 128;

  // ---- QK^T into registers ----
  f32x4 st[8];
  {
    short8 qh0 = *reinterpret_cast<const short8*>(Qh + qoff + lm * NDK + lg * 8);
    short8 qh1 = *reinterpret_cast<const short8*>(Qh + qoff + lm * NDK + 32 + lg * 8);
    short8 ql0 = *reinterpret_cast<const short8*>(Ql + qoff + lm * NDK + lg * 8);
    short8 ql1 = *reinterpret_cast<const short8*>(Ql + qoff + lm * NDK + 32 + lg * 8);
#pragma unroll
    for (int kt = 0; kt < 8; kt++) {
      size_t ko = (size_t)(kvbase + kt * 16) * NDK;
      const unsigned short* kh = Kph + ko + lm * NDK + lg * 8;
      const unsigned short* kl = Kpl + ko + lm * NDK + lg * 8;
      short8 ah0 = *reinterpret_cast<const short8*>(kh);
      short8 ah1 = *reinterpret_cast<const short8*>(kh + 32);
      short8 al0 = *reinterpret_cast<const short8*>(kl);
      short8 al1 = *reinterpret_cast<const short8*>(kl + 32);
      f32x4 a0 = (f32x4){0.f, 0.f, 0.f, 0.f};
      f32x4 a1 = (f32x4){0.f, 0.f, 0.f, 0.f};
      a0 = __builtin_amdgcn_mfma_f32_16x16x32_bf16(ah0, qh0, a0, 0, 0, 0);
      a1 = __builtin_amdgcn_mfma_f32_16x16x32_bf16(ah1, qh1, a1, 0, 0, 0);
      a0 = __builtin_amdgcn_mfma_f32_16x16x32_bf16(al0, qh0, a0, 0, 0, 0);
      a1 = __builtin_amdgcn_mfma_f32_16x16x32_bf16(al1, qh1, a1, 0, 0, 0);
      a0 = __builtin_amdgcn_mfma_f32_16x16x32_bf16(ah0, ql0, a0, 0, 0, 0);
      a1 = __builtin_amdgcn_mfma_f32_16x16x32_bf16(ah1, ql1, a1, 0, 0, 0);
      st[kt] = (a0 + a1) * 0.125f;  // 1/sqrt(64)
    }
  }

  // ---- softmax + sparsification: intra-lane -> shfl -> tiny LDS cross-wave ----
  float cut, inv;
  {
    float m = -1e30f;
#pragma unroll
    for (int kt = 0; kt < 8; kt++)
      m = fmaxf(m, fmaxf(fmaxf(st[kt][0], st[kt][1]), fmaxf(st[kt][2], st[kt][3])));
    m = fmaxf(m, __shfl_xor(m, 16));
    m = fmaxf(m, __shfl_xor(m, 32));
    if (lg == 0) part[0][wave][lm] = m;
    __syncthreads();
    float gm = -1e30f;
#pragma unroll
    for (int w = 0; w < 16; w++) gm = fmaxf(gm, part[0][w][lm]);

    float E = 0.f;
#pragma unroll
    for (int kt = 0; kt < 8; kt++) {
#pragma unroll
      for (int j = 0; j < 4; j++) {
        float e = __expf(st[kt][j] - gm);
        st[kt][j] = e;
        E += e;
      }
    }
    E += __shfl_xor(E, 16);
    E += __shfl_xor(E, 32);
    if (lg == 0) part[1][wave][lm] = E;
    __syncthreads();
    float gE = 0.f;
#pragma unroll
    for (int w = 0; w < 16; w++) gE += part[1][w][lm];

    const float thr[3] = {1.0f / 2048.0f, 1.0f / (0.6f * 2048.0f), 1.0f / (0.36f * 2048.0f)};
    float Dd = 1.0f;
    cut = 0.f;
#pragma unroll
    for (int t = 0; t < 3; t++) {
      cut = fmaxf(cut, thr[t] * Dd * gE);
      float S = 0.f;
#pragma unroll
      for (int kt = 0; kt < 8; kt++) {
#pragma unroll
        for (int j = 0; j < 4; j++) S += (st[kt][j] >= cut) ? st[kt][j] : 0.f;
      }
      S += __shfl_xor(S, 16);
      S += __shfl_xor(S, 32);
      if (lg == 0) part[2 + t][wave][lm] = S;
      __syncthreads();
      float gS = 0.f;
#pragma unroll
      for (int w = 0; w < 16; w++) gS += part[2 + t][w][lm];
      Dd = gS / gE + 1e-9f * Dd;
    }
    inv = 1.0f / (gE * Dd);  // final w = e * inv on kept set
  }

  // ---- PV: on-the-fly conversion + cross-lane shuffle A-frags; wave covers its kv slice ----
  {
    const int e_lane = lm + 32 * (lg & 1);
    const int o_lane = e_lane + 16;
    const bool selB = (lane & 32) != 0;
    f32x4 acc[4];
#pragma unroll
    for (int dt = 0; dt < 4; dt++) acc[dt] = (f32x4){0.f, 0.f, 0.f, 0.f};
#pragma unroll
    for (int wi = 0; wi < 4; wi++) {
      // convert this 32-kv window's weights (each value converted exactly once)
      unsigned int cw[8];  // [A0h,A1h,B0h,B1h, A0l,A1l,B0l,B1l]
#pragma unroll
      for (int half = 0; half < 2; half++) {
        f32x4 s = st[2 * wi + half];
#pragma unroll
        for (int rp = 0; rp < 2; rp++) {
          float w0 = s[2 * rp], w1 = s[2 * rp + 1];
          w0 = (w0 >= cut) ? w0 * inv : 0.f;
          w1 = (w1 >= cut) ? w1 * inv : 0.f;
          unsigned int h0 = f2bfu(w0), h1 = f2bfu(w1);
          cw[half * 2 + rp] = h0 | (h1 << 16);
          unsigned int l0 = f2bfu(w0 - bfu2f((unsigned short)h0));
          unsigned int l1 = f2bfu(w1 - bfu2f((unsigned short)h1));
          cw[4 + half * 2 + rp] = l0 | (l1 << 16);
        }
      }
      unsigned int a0 = (unsigned)__shfl((int)cw[0], e_lane);
      unsigned int a1 = (unsigned)__shfl((int)cw[1], e_lane);
      unsigned int a2 = (unsigned)__shfl((int)cw[0], o_lane);
      unsigned int a3 = (unsigned)__shfl((int)cw[1], o_lane);
      unsigned int b0 = (unsigned)__shfl((int)cw[2], e_lane);
      unsigned int b1 = (unsigned)__shfl((int)cw[3], e_lane);
      unsigned int b2 = (unsigned)__shfl((int)cw[2], o_lane);
      unsigned int b3 = (unsigned)__shfl((int)cw[3], o_lane);
      u32x4 hw = (u32x4){selB ? b0 : a0, selB ? b1 : a1, selB ? b2 : a2, selB ? b3 : a3};
      a0 = (unsigned)__shfl((int)cw[4], e_lane);
      a1 = (unsigned)__shfl((int)cw[5], e_lane);
      a2 = (unsigned)__shfl((int)cw[4], o_lane);
      a3 = (unsigned)__shfl((int)cw[5], o_lane);
      b0 = (unsigned)__shfl((int)cw[6], e_lane);
      b1 = (unsigned)__shfl((int)cw[7], e_lane);
      b2 = (unsigned)__shfl((int)cw[6], o_lane);
      b3 = (unsigned)__shfl((int)cw[7], o_lane);
      u32x4 lw = (u32x4){selB ? b0 : a0, selB ? b1 : a1, selB ? b2 : a2, selB ? b3 : a3};
      short8 Ah = __builtin_bit_cast(short8, hw);
      short8 Al = __builtin_bit_cast(short8, lw);
      const int co = kvbase + wi * 32 + lg * 8;
#pragma unroll
      for (int dt = 0; dt < 4; dt++) {
        short8 V0 = *reinterpret_cast<const short8*>(Vph + (size_t)(dt * 16 + lm) * NS + co);
        short8 V1 = *reinterpret_cast<const short8*>(Vpl + (size_t)(dt * 16 + lm) * NS + co);
        acc[dt] = __builtin_amdgcn_mfma_f32_16x16x32_bf16(Ah, V0, acc[dt], 0, 0, 0);
        acc[dt] = __builtin_amdgcn_mfma_f32_16x16x32_bf16(Ah, V1, acc[dt], 0, 0, 0);
        acc[dt] = __builtin_amdgcn_mfma_f32_16x16x32_bf16(Al, V0, acc[dt], 0, 0, 0);
      }
    }
#pragma unroll
    for (int dt = 0; dt < 4; dt++)
#pragma unroll
      for (int rr = 0; rr < 4; rr++) red[wave][lg * 4 + rr][dt * 16 + lm] = acc[dt][rr];
  }
  __syncthreads();

  // ---- reduce 16 wave-partials; packed-uint writes to attn_cat [b*NS+s][1536] ----
  if (tid < 512) {
    const int q = tid >> 5;          // 0..15
    const int dv0 = (tid & 31) * 2;  // 0..62 even
    const int b = bh >> 3, h = bh & 7;
    const int s = q0 + q;
    float v0 = 0.f, v1 = 0.f;
#pragma unroll
    for (int w = 0; w < 16; w++) {
      float2 rr = *reinterpret_cast<const float2*>(&red[w][q][dv0]);
      v0 += rr.x;
      v1 += rr.y;
    }
    unsigned short h0 = f2bfu(v0), h1 = f2bfu(v1);
    unsigned int hw = (unsigned int)h0 | ((unsigned int)h1 << 16);
    unsigned int lw = (unsigned int)f2bfu(v0 - bfu2f(h0)) |
                      ((unsigned int)f2bfu(v1 - bfu2f(h1)) << 16);
    unsigned int* out32 = reinterpret_cast<unsigned int*>(attn + ((size_t)b * NS + s) * 1536);
    int cwi = h * 32 + (dv0 >> 1);
    out32[cwi] = hw;
    out32[cwi + 256] = hw;
    out32[cwi + 512] = lw;
  }
}

// ---------------- launch ----------------

extern "C" void kernel_launch(void* const* d_in, const int* in_sizes, int n_in,
                              void* d_out, int out_size, void* d_ws, size_t ws_size,
                              hipStream_t stream) {
  const float* x  = (const float*)d_in[0];
  const float* Wq = (const float*)d_in[1];
  const float* bq = (const float*)d_in[2];
  const float* Wk = (const float*)d_in[3];
  const float* bk = (const float*)d_in[4];
  const float* Wv = (const float*)d_in[5];
  const float* bv = (const float*)d_in[6];
  const float* Wo = (const float*)d_in[7];
  const float* bo = (const float*)d_in[8];

  char* ws = (char*)d_ws;
  size_t off = 0;
  auto alloc = [&](size_t bytes) {
    char* p = ws + off;
    off += (bytes + 255) & ~(size_t)255;
    return p;
  };
  const int M = NB * NS;  // 8192
  unsigned short* xcat = (unsigned short*)alloc((size_t)M * 1536 * 2);  // reused as attn_cat
  unsigned short* wqC  = (unsigned short*)alloc((size_t)512 * 1536 * 2);
  unsigned short* wkC  = (unsigned short*)alloc((size_t)512 * 1536 * 2);
  unsigned short* wvC  = (unsigned short*)alloc((size_t)512 * 1536 * 2);
  unsigned short* woC  = (unsigned short*)alloc((size_t)512 * 1536 * 2);
  unsigned short* Qhi  = (unsigned short*)alloc((size_t)M * 512 * 2);
  unsigned short* Qlo  = (unsigned short*)alloc((size_t)M * 512 * 2);
  unsigned short* Khi  = (unsigned short*)alloc((size_t)M * 512 * 2);
  unsigned short* Klo  = (unsigned short*)alloc((size_t)M * 512 * 2);
  unsigned short* Vthi = (unsigned short*)alloc((size_t)M * 512 * 2);
  unsigned short* Vtlo = (unsigned short*)alloc((size_t)M * 512 * 2);
  unsigned short* attn = xcat;  // alias: xcat dead after V projection

  k_make_xcat<<<(M * 512 / 4 + 255) / 256, 256, 0, stream>>>(x, xcat, M * 512 / 4);

  dim3 tg(16, 16), tb(32, 8);
  k_transpose_split<<<tg, tb, 0, stream>>>(Wq, wqC, ND, NH * NDK);
  k_transpose_split<<<tg, tb, 0, stream>>>(Wk, wkC, ND, NH * NDK);
  k_transpose_split<<<tg, tb, 0, stream>>>(Wv, wvC, ND, NH * NDV);
  k_transpose_split<<<tg, tb, 0, stream>>>(Wo, woC, NH * NDV, ND);

  dim3 gg(512 / 64, M / 64);
  k_gemm_nt<0><<<gg, 256, 0, stream>>>(xcat, wqC, bq, Qhi, Qlo, M, 512, 1536);
  k_gemm_nt<0><<<gg, 256, 0, stream>>>(xcat, wkC, bk, Khi, Klo, M, 512, 1536);
  k_gemm_nt<2><<<gg, 256, 0, stream>>>(xcat, wvC, bv, Vthi, Vtlo, M, 512, 1536);

  k_sparse_attn<<<NB * NH * (NS / 16), 1024, 0, stream>>>(Qhi, Qlo, Khi, Klo, Vthi, Vtlo, attn);

  k_gemm_nt<3><<<gg, 256, 0, stream>>>(attn, woC, bo, d_out, nullptr, M, 512, 1536);
}